// Round 1
// baseline (403.750 us; speedup 1.0000x reference)
//
#include <hip/hip_runtime.h>
#include <math.h>

// Problem: B=4, S=4096, D=2048, E=64, K=2
//   logits = x[BS, D] @ w[E, D]^T ; probs = softmax(logits); top-2 + renorm
// Output layout (flat f32): idx[BS*2] | topk_probs[BS*2] | probs[BS*64]

#define TOK   16384   // B*S
#define DD    2048
#define EE    64
#define BM    64      // tokens per block
#define BK    64      // k-chunk
#define NCH   (DD / BK)   // 32

#define OUT_IDX   0
#define OUT_TP    (TOK * 2)        // 32768
#define OUT_PROBS (TOK * 4)        // 65536

__global__ __launch_bounds__(256, 1)
void router_fused(const float* __restrict__ x, const float* __restrict__ w,
                  float* __restrict__ out) {
    __shared__ float xs[BM][BK + 4];      // +4 pad: rows 272B (16B-aligned), reads 2-way
    __shared__ float ws[BK][EE];          // transposed w chunk: conflict-free B-frag reads
    __shared__ float lg[BM][EE + 1];      // logits staging for epilogue
    __shared__ float smax[BM], sinv[BM];

    const int tid = threadIdx.x;
    const int g0  = blockIdx.x * BM;      // first token of this block

    const int tx = tid & 15;              // expert group: experts tx*4..tx*4+3
    const int ty = tid >> 4;              // token group:  tokens ty*4..ty*4+3

    float acc[4][4] = {{0.f}};

    // staging map: 4 threads per row, each 64 contiguous bytes
    const int mr = tid >> 2;              // row (token for x, expert for w), 0..63
    const int kx = (tid & 3) * 16;        // k offset within chunk
    const float* xrow = x + (size_t)(g0 + mr) * DD + kx;
    const float* wrow = w + (size_t)mr * DD + kx;

    float4 nx[4], nw[4];

    // ---- prologue: stage chunk 0 ----
#pragma unroll
    for (int r = 0; r < 4; ++r) {
        nx[r] = *(const float4*)(xrow + r * 4);
        nw[r] = *(const float4*)(wrow + r * 4);
    }
#pragma unroll
    for (int r = 0; r < 4; ++r) {
        *(float4*)&xs[mr][kx + r * 4] = nx[r];
        ws[kx + r * 4 + 0][mr] = nw[r].x;
        ws[kx + r * 4 + 1][mr] = nw[r].y;
        ws[kx + r * 4 + 2][mr] = nw[r].z;
        ws[kx + r * 4 + 3][mr] = nw[r].w;
    }
    __syncthreads();

#define FMA_ROW(i, XC, K)                                   \
    acc[i][0] = fmaf(XC, wv[K].x, acc[i][0]);               \
    acc[i][1] = fmaf(XC, wv[K].y, acc[i][1]);               \
    acc[i][2] = fmaf(XC, wv[K].z, acc[i][2]);               \
    acc[i][3] = fmaf(XC, wv[K].w, acc[i][3]);

    // ---- main loop: T14 split (issue loads early, ds_write late) ----
    for (int c = 0; c < NCH; ++c) {
        if (c + 1 < NCH) {
            const float* xp = xrow + (c + 1) * BK;
            const float* wp = wrow + (c + 1) * BK;
#pragma unroll
            for (int r = 0; r < 4; ++r) {
                nx[r] = *(const float4*)(xp + r * 4);
                nw[r] = *(const float4*)(wp + r * 4);
            }
        }
#pragma unroll
        for (int k4 = 0; k4 < BK / 4; ++k4) {
            float4 xv[4], wv[4];
#pragma unroll
            for (int i = 0; i < 4; ++i)
                xv[i] = *(const float4*)&xs[ty * 4 + i][k4 * 4];
#pragma unroll
            for (int k = 0; k < 4; ++k)
                wv[k] = *(const float4*)&ws[k4 * 4 + k][tx * 4];
#pragma unroll
            for (int i = 0; i < 4; ++i) {
                FMA_ROW(i, xv[i].x, 0)
                FMA_ROW(i, xv[i].y, 1)
                FMA_ROW(i, xv[i].z, 2)
                FMA_ROW(i, xv[i].w, 3)
            }
        }
        __syncthreads();
        if (c + 1 < NCH) {
#pragma unroll
            for (int r = 0; r < 4; ++r) {
                *(float4*)&xs[mr][kx + r * 4] = nx[r];
                ws[kx + r * 4 + 0][mr] = nw[r].x;
                ws[kx + r * 4 + 1][mr] = nw[r].y;
                ws[kx + r * 4 + 2][mr] = nw[r].z;
                ws[kx + r * 4 + 3][mr] = nw[r].w;
            }
            __syncthreads();
        }
    }

    // ---- epilogue: logits -> LDS ----
#pragma unroll
    for (int i = 0; i < 4; ++i)
#pragma unroll
        for (int j = 0; j < 4; ++j)
            lg[ty * 4 + i][tx * 4 + j] = acc[i][j];
    __syncthreads();

    // pass 1: per-token max, top-2, exp-sum (threads 0..63)
    if (tid < BM) {
        const int t = tid;
        float v1 = -INFINITY, v2 = -INFINITY;
        int i1 = 0, i2 = 0;
#pragma unroll
        for (int e = 0; e < EE; ++e) {
            float l = lg[t][e];
            if (l > v1)      { v2 = v1; i2 = i1; v1 = l; i1 = e; }
            else if (l > v2) { v2 = l; i2 = e; }
        }
        float s = 0.f;
#pragma unroll
        for (int e = 0; e < EE; ++e) s += expf(lg[t][e] - v1);
        float inv = 1.f / s;
        float p1 = inv;                        // expf(v1-v1) * inv
        float p2 = expf(v2 - v1) * inv;
        float den = p1 + p2 + 1e-9f;
        const int g = g0 + t;
        out[OUT_IDX + (size_t)g * 2 + 0] = (float)i1;
        out[OUT_IDX + (size_t)g * 2 + 1] = (float)i2;
        out[OUT_TP  + (size_t)g * 2 + 0] = p1 / den;
        out[OUT_TP  + (size_t)g * 2 + 1] = p2 / den;
        smax[t] = v1;
        sinv[t] = inv;
    }
    __syncthreads();

    // pass 2: coalesced probs write (all 256 threads, 4 float4 each)
    float* probs = out + OUT_PROBS;
#pragma unroll
    for (int r = 0; r < 4; ++r) {
        int f   = tid + r * 256;               // float4 index, 0..1023
        int row = f >> 4;                      // 0..63
        int c4  = (f & 15) * 4;                // 0..60
        float m = smax[row], iv = sinv[row];
        float4 o;
        o.x = expf(lg[row][c4 + 0] - m) * iv;
        o.y = expf(lg[row][c4 + 1] - m) * iv;
        o.z = expf(lg[row][c4 + 2] - m) * iv;
        o.w = expf(lg[row][c4 + 3] - m) * iv;
        *(float4*)(probs + (size_t)(g0 + row) * EE + c4) = o;
    }
}

extern "C" void kernel_launch(void* const* d_in, const int* in_sizes, int n_in,
                              void* d_out, int out_size, void* d_ws, size_t ws_size,
                              hipStream_t stream) {
    const float* x = (const float*)d_in[0];   // [4,4096,2048] f32
    const float* w = (const float*)d_in[1];   // [64,2048] f32
    float* out = (float*)d_out;
    router_fused<<<TOK / BM, 256, 0, stream>>>(x, w, out);
}